// Round 16
// baseline (124.964 us; speedup 1.0000x reference)
//
#include <hip/hip_runtime.h>
#include <hip/hip_bf16.h>
#include <stdint.h>

#define N 8192
#define E 256
#define NUM_CLASSES 100
#define MARGIN 0.1f
#define EPS 1e-4f

#define BT 128                      // Gram tile dim
#define MT (N / BT)                 // 64 tile-rows
#define NTILES (MT * (MT + 1) / 2)  // 2080 upper-tri tiles
#define SL (2 * MT)                 // 128 partial slices (2 per tile index)
#define EB 256                      // fp8 row = 256 B
#define FINB 128                    // fin blocks

typedef __attribute__((ext_vector_type(4))) float floatx4;
typedef __attribute__((ext_vector_type(2))) long longx2;
typedef const __attribute__((address_space(1))) void* gptr_t;
typedef __attribute__((address_space(3))) void* sptr_t;

struct Ctrl { double Ssum; int c2; };  // zeroed by prep block 0

// 16-lane butterfly sum on the VALU via DPP (no LDS-pipe usage).
__device__ __forceinline__ float dpp_sum16(float v) {
  v += __int_as_float(__builtin_amdgcn_update_dpp(0, __float_as_int(v), 0xB1, 0xF, 0xF, true));
  v += __int_as_float(__builtin_amdgcn_update_dpp(0, __float_as_int(v), 0x4E, 0xF, 0xF, true));
  v += __int_as_float(__builtin_amdgcn_update_dpp(0, __float_as_int(v), 0x141, 0xF, 0xF, true));
  v += __int_as_float(__builtin_amdgcn_update_dpp(0, __float_as_int(v), 0x140, 0xF, 0xF, true));
  return v;
}

// linear upper-triangle tile id -> (by, bx), bx >= by  (f32)
__device__ __forceinline__ void decode_tile(int t, int& by, int& bx) {
  const float M2 = 2.0f * MT + 1.0f;
  int y = (int)((M2 - __builtin_sqrtf(M2 * M2 - 8.0f * (float)t)) * 0.5f);
  while (y * MT - y * (y - 1) / 2 > t) --y;
  while ((y + 1) * MT - (y + 1) * y / 2 <= t) ++y;
  by = y;
  bx = y + (t - (y * MT - y * (y - 1) / 2));
}

// --- Kernel 1: fp8 cast into INTERLEAVED-K layout + row norms ---------------
__global__ __launch_bounds__(256) void prep_kernel(
    const float* __restrict__ emb, unsigned char* __restrict__ Efp8,
    float* __restrict__ sq, Ctrl* __restrict__ ctrl)
{
  const int lane = threadIdx.x & 63;
  const int wave = threadIdx.x >> 6;
  if (blockIdx.x == 0 && threadIdx.x == 0) {
    ctrl->Ssum = 0.0;
    ctrl->c2 = 0;
  }
  const int d = lane;
  const int src = (d & 32) | (((d >> 1) & 1) << 4) | (((d >> 2) & 7) << 1) | (d & 1);
  #pragma unroll
  for (int i = 0; i < 4; ++i) {
    const int row = blockIdx.x * 16 + i * 4 + wave;
    const float4 x = *(const float4*)(emb + (size_t)row * E + src * 4);
    int pk = __builtin_amdgcn_cvt_pk_fp8_f32(x.x, x.y, 0, false);
    pk = __builtin_amdgcn_cvt_pk_fp8_f32(x.z, x.w, pk, true);
    ((unsigned int*)(Efp8 + (size_t)row * EB))[d] = (unsigned int)pk;
    float s = x.x * x.x + x.y * x.y + x.z * x.z + x.w * x.w;
    #pragma unroll
    for (int off = 32; off > 0; off >>= 1) s += __shfl_down(s, off, 64);
    if (lane == 0) sq[row] = s;
  }
}

// --- Kernel 2: fp8 MFMA Gram (R20 = A-staged LDS, B direct from L2) ---------
// Plateau model (R19 post-mortem): gram = {VALU 13, LDS-pipe 10, L2 4,
// MFMA 4} us busy across four pipes, serialized by intra-block phase deps
// with only 2-way block desync -> 36.5. Six levers null/regressed.
// R20 attacks the LDS phase: stage ONLY A (32 KB); B-fragments read direct
// from L2 (R6-verified coalesced pattern: 16 rows x 64 B per wave-load,
// Efp8 L2-resident; R6's latency exposure cured here by 8 waves/SIMD).
// Halves staging writes, removes 4x-amplified B LDS reads (~7 us/CU),
// halves the vmcnt drain, drops the diag special-case.
// Tripwires: total > 107 => revert R19, declare plateau; WRITE > 9 MB =>
// spill from B-address registers.
__global__ __launch_bounds__(512, 4) void gram_kernel(
    const unsigned char* __restrict__ Efp8, const float* __restrict__ sq,
    const int* __restrict__ labels, float* __restrict__ numpart,
    float* __restrict__ denpart)
{
  __shared__ alignas(16) unsigned char As[BT * 256];  // 32 KB (both slabs)
  __shared__ float cn[8][64];                         // 2 KB col-fold
  __shared__ float cd[8][64];                         // 2 KB

  int by, bx;
  decode_tile(blockIdx.x, by, bx);
  const bool diag = (bx == by);

  const int tid = threadIdx.x;
  const int lane = tid & 63;
  const int wave = tid >> 6;          // 0..7
  const int waveM = wave >> 1;        // 0..3 : 32-row chunk
  const int waveN = wave & 1;         // 0..1 : 64-col chunk
  const int quad = lane >> 4;
  const int l16 = lane & 15;
  const char* gbase = (const char*)Efp8;

  // A staging (factored, byte-identical to verified layout).
  const int r0 = tid >> 3;
  const int u0 = (tid & 7) ^ (r0 & 7);
  const int ld0 = tid * 16;
  {
    const char* g0 = gbase + ((size_t)(by * BT + r0) << 8) + (u0 << 4);
    const char* g1 = g0 + 16384; /* +64 rows */
    __builtin_amdgcn_global_load_lds((gptr_t)g0, (sptr_t)(As + ld0), 16, 0, 0);
    __builtin_amdgcn_global_load_lds((gptr_t)g1, (sptr_t)(As + ld0 + 8192), 16, 0, 0);
    __builtin_amdgcn_global_load_lds((gptr_t)(g0 + 128), (sptr_t)(As + ld0 + 16384), 16, 0, 0);
    __builtin_amdgcn_global_load_lds((gptr_t)(g1 + 128), (sptr_t)(As + ld0 + 24576), 16, 0, 0);
  }
  __syncthreads();  // vmcnt(0) drain: A slab staged (half of R19's loads)

  // A fragment read bases (xo0 shared since r&7 == l16&7 for all fragments).
  const int xo0 = (quad ^ (l16 & 7)) << 4;
  const int xo1 = xo0 ^ 64;
  const unsigned char* aA0 = As + l16 * 128 + waveM * 4096 + xo0;
  const unsigned char* aA1 = As + l16 * 128 + waveM * 4096 + xo1;

  // B fragment base: direct global (R6-verified). Fragment (s,j,ni) at
  // row colBase + waveN*64 + ni*16 + l16, byte s*128 + j*64 + quad*16.
  const char* Bb = gbase + (size_t)(bx * BT + waveN * 64 + l16) * EB + quad * 16;

  floatx4 acc[2][4];
  #pragma unroll
  for (int a = 0; a < 2; ++a)
    #pragma unroll
    for (int b = 0; b < 4; ++b)
      acc[a][b] = (floatx4){0.f, 0.f, 0.f, 0.f};

  __builtin_amdgcn_s_setprio(1);
  #pragma unroll
  for (int s = 0; s < 2; ++s) {
    #pragma unroll
    for (int j = 0; j < 2; ++j) {
      const unsigned char* aj = (j ? aA1 : aA0) + s * 16384;
      longx2 afj[2], bfj[4];
      #pragma unroll
      for (int mi = 0; mi < 2; ++mi)
        afj[mi] = *(const longx2*)(aj + mi * 2048);
      #pragma unroll
      for (int ni = 0; ni < 4; ++ni)
        bfj[ni] = *(const longx2*)(Bb + ni * 16 * EB + s * 128 + j * 64);
      #pragma unroll
      for (int h = 0; h < 2; ++h)  // low 8 B = step j, high 8 B = step j+2
        #pragma unroll
        for (int mi = 0; mi < 2; ++mi)
          #pragma unroll
          for (int ni = 0; ni < 4; ++ni)
            acc[mi][ni] = __builtin_amdgcn_mfma_f32_16x16x32_fp8_fp8(
                afj[mi][h], bfj[ni][h], acc[mi][ni], 0, 0, 0);
    }
  }
  __builtin_amdgcn_s_setprio(0);

  const int rowBase = by * BT;
  const int colBase = bx * BT;

  // ---- epilogue: registers + DPP + plain unique-writer stores --------------
  float sqc[4];
  int lc[4];
  #pragma unroll
  for (int ni = 0; ni < 4; ++ni) {
    const int col = colBase + waveN * 64 + ni * 16 + l16;
    sqc[ni] = sq[col];
    lc[ni] = labels[col];
  }

  float ncp[4] = {0.f, 0.f, 0.f, 0.f};
  float dcp[4] = {0.f, 0.f, 0.f, 0.f};

  #pragma unroll
  for (int mi = 0; mi < 2; ++mi) {
    const int rbase = rowBase + waveM * 32 + mi * 16 + quad * 4;
    const float4 sqr4 = *(const float4*)(sq + rbase);
    const int4 lr4 = *(const int4*)(labels + rbase);
    const float sqr[4] = {sqr4.x, sqr4.y, sqr4.z, sqr4.w};
    const int lr[4] = {lr4.x, lr4.y, lr4.z, lr4.w};
    float npv[4], dpv[4];
    #pragma unroll
    for (int r = 0; r < 4; ++r) {
      float np = 0.f, dp = 0.f;
      #pragma unroll
      for (int ni = 0; ni < 4; ++ni) {
        float d2 = fmaxf(fmaf(-2.f, acc[mi][ni][r], sqr[r] + sqc[ni]), EPS);
        // diagonal element: 16-row chunk match and in-chunk match
        if (diag && (waveM * 2 + mi == waveN * 4 + ni) && (quad * 4 + r == l16))
          d2 = EPS;
        // rsqrt-based: d = d2*rsq; 1/(d+m) ~ rsq*(1-x+x^2), x = m*rsq.
        const float rsq = __builtin_amdgcn_rsqf(d2);
        const float x = MARGIN * rsq;
        const float rc = rsq * (fmaf(x, x, 1.f) - x);
        const float dv = d2 * rsq;
        const bool same = (lr[r] == lc[ni]);
        const float dsel = same ? dv : 0.f;
        const float rsel = same ? 0.f : rc;
        np += dsel; dp += rsel;
        ncp[ni] += dsel; dcp[ni] += rsel;
      }
      npv[r] = dpp_sum16(np);
      dpv[r] = dpp_sum16(dp);
    }
    const float seln = (l16 & 2) ? ((l16 & 1) ? npv[3] : npv[2])
                                 : ((l16 & 1) ? npv[1] : npv[0]);
    const float seld = (l16 & 2) ? ((l16 & 1) ? dpv[3] : dpv[2])
                                 : ((l16 & 1) ? dpv[1] : dpv[0]);
    if ((l16 >> 2) == quad) {  // one lane per row; per-waveN slice
      const int row = rowBase + waveM * 32 + mi * 16 + l16;
      numpart[(size_t)(2 * bx + waveN) * N + row] = seln;
      denpart[(size_t)(2 * bx + waveN) * N + row] = seld;
    }
  }

  // col partials: in-wave quad reduce -> LDS fold (waveM pairs) -> store
  if (!diag) {
    #pragma unroll
    for (int ni = 0; ni < 4; ++ni) {
      float n2 = ncp[ni], d2 = dcp[ni];
      n2 += __shfl_xor(n2, 16, 64); d2 += __shfl_xor(d2, 16, 64);
      n2 += __shfl_xor(n2, 32, 64); d2 += __shfl_xor(d2, 32, 64);
      if (quad == 0) {
        cn[wave][ni * 16 + l16] = n2;
        cd[wave][ni * 16 + l16] = d2;
      }
    }
  }
  __syncthreads();
  if (!diag && (waveM & 1) == 0) {  // waves 0,1,4,5: fold wave and wave+2
    const float n2 = cn[wave][lane] + cn[wave + 2][lane];
    const float d2v = cd[wave][lane] + cd[wave + 2][lane];
    const int col = colBase + waveN * 64 + lane;
    numpart[(size_t)(2 * by + (wave >> 2)) * N + col] = n2;
    denpart[(size_t)(2 * by + (wave >> 2)) * N + col] = d2v;
  }
}

// --- Kernel 3: fold 128 slices, S-reduce, last block m_sum + divide ---------
__global__ __launch_bounds__(256) void fin_kernel(
    const float* __restrict__ numpart, const float* __restrict__ denpart,
    const int* __restrict__ labels, Ctrl* __restrict__ ctrl,
    float* __restrict__ out)
{
  __shared__ double sh[4];
  __shared__ int lastflag;
  __shared__ int hist[NUM_CLASSES];
  __shared__ double shm[4];

  const int tid = threadIdx.x;
  const int lane = tid & 63;
  const int wave = tid >> 6;
  const int sub = lane >> 4;
  const int l16 = lane & 15;
  const int a = blockIdx.x * 64 + wave * 16 + l16;

  float np = 0.f, dp = 0.f;
  #pragma unroll 4
  for (int i = 0; i < 32; ++i) {
    const int k = sub * 32 + i;
    np += numpart[(size_t)k * N + a];
    dp += denpart[(size_t)k * N + a];
  }
  np += __shfl_xor(np, 16, 64); dp += __shfl_xor(dp, 16, 64);
  np += __shfl_xor(np, 32, 64); dp += __shfl_xor(dp, 32, 64);

  double s = (sub == 0) ? (double)np * (double)dp : 0.0;
  #pragma unroll
  for (int off = 32; off > 0; off >>= 1) s += __shfl_down(s, off, 64);
  if (lane == 0) sh[wave] = s;
  __syncthreads();
  if (tid == 0) {
    unsafeAtomicAdd(&ctrl->Ssum, sh[0] + sh[1] + sh[2] + sh[3]);
    __threadfence();
    const int prev = __hip_atomic_fetch_add(&ctrl->c2, 1, __ATOMIC_ACQ_REL,
                                            __HIP_MEMORY_SCOPE_AGENT);
    lastflag = (prev == FINB - 1) ? 1 : 0;
  }
  __syncthreads();

  if (lastflag) {
    if (tid < NUM_CLASSES) hist[tid] = 0;
    __syncthreads();
    for (int i = tid; i < N; i += 256) atomicAdd(&hist[labels[i]], 1);
    __syncthreads();
    double m = 0.0;
    if (tid < NUM_CLASSES) {
      const double cc = (double)hist[tid];
      m = cc * cc * (double)(N - cc);
    }
    #pragma unroll
    for (int off = 32; off > 0; off >>= 1) m += __shfl_down(m, off, 64);
    if (lane == 0) shm[wave] = m;
    __syncthreads();
    if (tid == 0) {
      const double M = shm[0] + shm[1] + shm[2] + shm[3];
      const double S = __hip_atomic_load(&ctrl->Ssum, __ATOMIC_ACQUIRE,
                                         __HIP_MEMORY_SCOPE_AGENT);
      out[0] = (float)(S / M);
    }
  }
}

extern "C" void kernel_launch(void* const* d_in, const int* in_sizes, int n_in,
                              void* d_out, int out_size, void* d_ws, size_t ws_size,
                              hipStream_t stream) {
  const float* emb = (const float*)d_in[0];
  const int* labels = (const int*)d_in[1];
  float* out = (float*)d_out;

  // ws: Efp8[2MB] | sq[32KB] | numpart[4MB] | denpart[4MB] | Ctrl  (~10 MB)
  char* w = (char*)d_ws;
  unsigned char* Efp8 = (unsigned char*)w;
  float* sq = (float*)(w + (size_t)N * EB);
  float* numpart = sq + N;
  float* denpart = numpart + (size_t)SL * N;
  Ctrl* ctrl = (Ctrl*)(denpart + (size_t)SL * N);

  prep_kernel<<<N / 16, 256, 0, stream>>>(emb, Efp8, sq, ctrl);
  gram_kernel<<<NTILES, 512, 0, stream>>>(Efp8, sq, labels, numpart, denpart);
  fin_kernel<<<FINB, 256, 0, stream>>>(numpart, denpart, labels, ctrl, out);
}